// Round 8
// baseline (327.752 us; speedup 1.0000x reference)
//
#include <hip/hip_runtime.h>
#include <hip/hip_bf16.h>
#include <hip/hip_cooperative_groups.h>
#include <math.h>

typedef __attribute__((ext_vector_type(8))) short bf16x8v;
typedef __attribute__((ext_vector_type(4))) float f32x4v;
typedef __attribute__((ext_vector_type(4))) unsigned u32x4v;

namespace cg = cooperative_groups;

namespace {

constexpr float PI_F      = 3.14159265358979323846f;
constexpr float TWO_PI_F  = 6.28318530717958647692f;
constexpr float INV_2PI_F = 0.15915494309189533577f;
constexpr float ZC_F      = 0.86602540378443864676f;

__device__ __constant__ float d_BOUNDS[8] = {0.1f, 0.2f, 0.4f, 0.6f, 0.75f,
                                             0.8660254037844386f, 0.92f, 0.97f};
__device__ __constant__ float d_PARITY[6] = {1.f, -1.f, 1.f, 1.f, -1.f, -1.f};
__device__ __constant__ int d_LEGAL[9][6] = {
    {0, 0, 0, 1, 1, 1},
    {1, 0, 1, 0, 1, 1},
    {1, 1, 1, 0, 1, 1},
    {0, 1, 0, 1, 1, 1},
    {1, 1, 1, 1, 1, 1},
    {0, 1, 0, 1, 1, 1},
    {0, 1, 0, 1, 0, 0},
    {0, 1, 1, 1, 0, 0},
    {0, 1, 1, 1, 0, 0}};

__device__ __forceinline__ float wave_sum(float v) {
#pragma unroll
  for (int o = 32; o > 0; o >>= 1) v += __shfl_xor(v, o, 64);
  return v;
}

__device__ __forceinline__ float gelu_exact(float x) {
  return 0.5f * x * (1.0f + erff(x * 0.70710678118654752440f));
}

__device__ __forceinline__ unsigned short f2b(float v) {
  return __builtin_bit_cast(unsigned short, __float2bfloat16(v));
}

__device__ __forceinline__ unsigned pkbf(float a, float b) {
  return ((unsigned)f2b(b) << 16) | (unsigned)f2b(a);
}

}  // namespace

// LDS pair-array stride (dwords): 32 pairs + 4 pad -> 2-way bank alias (free).
#define LSTR 36

struct Params {
  const float *x, *W_enc, *b_enc, *K, *omega, *Kglob, *aplK, *aplOm;
  const float *W1, *b1, *W2, *b2, *W3, *b3, *prior, *noise, *W_out, *b_out;
  unsigned short *Aenc, *Kb, *Wob;
  float *part, *row0cos, *coh0, *out;
};

// ---------------------------------------------------------------------------
// Single cooperative kernel: prep -> MFMA enc -> 4x(decide + 10 MFMA Kuramoto
// steps) -> MFMA out. 512 blocks x 256 thr (4 waves; 2 blocks/CU, 8 waves/CU).
// Block owns 16 batch cols; wave w owns osc tile w (rows 16w+4g+r per lane).
// State (th, sin, cos) register-resident across ALL layers. Cross-wave osc
// exchange via LDS (stride-36 pairs); batch-global z via part[] + grid sync.
// ---------------------------------------------------------------------------
__global__ __launch_bounds__(256, 2) void fused_net(Params p) {
  cg::grid_group grd = cg::this_grid();
  __shared__ float fe[64], hh[64], lgits[8], scal[4];
  __shared__ float redM[4][16][4];
  __shared__ unsigned sinL[16 * LSTR], cosL[16 * LSTR];
  __shared__ __align__(16) float trans[16][260];
  const int tid = threadIdx.x;
  const int w = tid >> 6;
  const int lane = tid & 63;
  const int c = lane & 15, g = lane >> 4;
  const int bid = blockIdx.x;
  const int b = bid * 16 + c;
  const bool pad = (w == 3) && (g == 3);
  const f32x4v z4 = {0.f, 0.f, 0.f, 0.f};

  // ---- prep: Aenc [64][512], Kb [4][64][64], Wob [256][128] (1 elem/thr) ---
  {
    const int t = bid * 256 + tid;
    if (t < 32768) {
      const int o = t >> 9, k = t & 511;
      p.Aenc[t] = f2b((o < 60) ? p.W_enc[k * 60 + o] : 0.f);
    } else if (t < 49152) {
      const int idx = t - 32768;
      const int l = idx >> 12, rem = idx & 4095, i = rem >> 6, k = rem & 63;
      p.Kb[idx] = f2b((i < 60 && k < 60) ? p.K[l * 3600 + i * 60 + k] : 0.f);
    } else if (t < 81920) {
      const int idx = t - 49152;
      const int d = idx >> 7, kk = idx & 127, prt = kk >> 6, o = kk & 63;
      p.Wob[idx] = f2b((o < 60) ? p.W_out[(prt * 60 + o) * 256 + d] : 0.f);
    }
  }
  grd.sync();

  float th[4], s4[4], c4[4];
  float chcol;

  // ---- encoder: th = pi*tanh(x @ W_enc + b_enc), straight into D-layout ----
  {
    f32x4v em = z4;
    const float* xr = p.x + (size_t)b * 512 + 8 * g;
    const unsigned short* ar = p.Aenc + (16 * w + c) * 512 + 8 * g;
#pragma unroll 4
    for (int kt = 0; kt < 16; ++kt) {
      const float4 u0 = *(const float4*)(xr + 32 * kt);
      const float4 u1 = *(const float4*)(xr + 32 * kt + 4);
      u32x4v bx;
      bx[0] = pkbf(u0.x, u0.y); bx[1] = pkbf(u0.z, u0.w);
      bx[2] = pkbf(u1.x, u1.y); bx[3] = pkbf(u1.z, u1.w);
      const bf16x8v A = *(const bf16x8v*)(ar + 32 * kt);
      em = __builtin_amdgcn_mfma_f32_16x16x32_bf16(
          A, __builtin_bit_cast(bf16x8v, bx), em, 0, 0, 0);
    }
    if (!pad) {
      const float4 be = *(const float4*)(p.b_enc + 16 * w + 4 * g);
      const float bea[4] = {be.x, be.y, be.z, be.w};
#pragma unroll
      for (int r = 0; r < 4; ++r) th[r] = PI_F * tanhf(em[r] + bea[r]);
    } else {
#pragma unroll
      for (int r = 0; r < 4; ++r) th[r] = 0.f;
    }
#pragma unroll
    for (int r = 0; r < 4; ++r) { s4[r] = __sinf(th[r]); c4[r] = __cosf(th[r]); }
    // coherence per col (cross-wave)
    float pcc = 0.f, pss = 0.f;
#pragma unroll
    for (int r = 0; r < 4; ++r) { pcc += c4[r]; pss += s4[r]; }
    pcc += __shfl_xor(pcc, 16); pcc += __shfl_xor(pcc, 32);
    pss += __shfl_xor(pss, 16); pss += __shfl_xor(pss, 32);
    redM[w][c][0] = pcc; redM[w][c][1] = pss;
    __syncthreads();
    float tc = 0.f, ts = 0.f;
#pragma unroll
    for (int ww = 0; ww < 4; ++ww) { tc += redM[ww][c][0]; ts += redM[ww][c][1]; }
    const float mc = (tc - 4.f) * (1.f / 60.f);
    const float ms = ts * (1.f / 60.f);
    chcol = sqrtf(mc * mc + ms * ms);
    const float tot = wave_sum(chcol) * 0.25f;
    if (tid == 0) p.part[bid] = tot;
    if (bid == 0) {
      if (c == 0 && !pad) {
#pragma unroll
        for (int r = 0; r < 4; ++r) p.row0cos[16 * w + 4 * g + r] = c4[r];
      }
      if (tid == 0) p.coh0[0] = chcol;
    }
  }
  grd.sync();

#pragma unroll 1
  for (int l = 0; l < 4; ++l) {
    // ---- decide (wave 0; redundant per block) ----
    float z = 0.f;
    int tier = 0;
    if (tid < 64) {
      const float4 p0 = *(const float4*)(p.part + l * 512 + 8 * lane);
      const float4 p1 = *(const float4*)(p.part + l * 512 + 8 * lane + 4);
      z = wave_sum(p0.x + p0.y + p0.z + p0.w + p1.x + p1.y + p1.z + p1.w) *
          (1.f / 8192.f);
#pragma unroll
      for (int i = 0; i < 8; ++i) tier += (z >= d_BOUNDS[i]) ? 1 : 0;
      const float dsneg = expf(-36.f * (z - ZC_F) * (z - ZC_F));
      const float* r0 = p.row0cos + 64 * (l & 1);
      fe[lane] = (lane < 60) ? r0[lane]
               : (lane == 60) ? z
               : (lane == 61) ? p.coh0[l & 1]
               : (lane == 62) ? dsneg
                              : (float)(tier + 1) * (1.f / 9.f);
    }
    __syncthreads();
    if (tid < 64) {
      float a1a = p.b1[l * 64 + lane], a1b = 0.f;
#pragma unroll 8
      for (int k = 0; k < 64; k += 2) {
        a1a = fmaf(fe[k], p.W1[l * 4096 + k * 64 + lane], a1a);
        a1b = fmaf(fe[k + 1], p.W1[l * 4096 + (k + 1) * 64 + lane], a1b);
      }
      hh[lane] = gelu_exact(a1a + a1b);
    }
    __syncthreads();
    float a2s = 0.f;
    if (tid < 64) {
      float a2a = p.b2[l * 64 + lane], a2b = 0.f;
#pragma unroll 8
      for (int k = 0; k < 64; k += 2) {
        a2a = fmaf(hh[k], p.W2[l * 4096 + k * 64 + lane], a2a);
        a2b = fmaf(hh[k + 1], p.W2[l * 4096 + (k + 1) * 64 + lane], a2b);
      }
      a2s = a2a + a2b;
    }
    __syncthreads();
    if (tid < 64) fe[lane] = gelu_exact(a2s);
    __syncthreads();
    if (tid < 6) {
      float a3 = p.b3[l * 6 + tid] + p.prior[l * 6 + tid];
#pragma unroll 8
      for (int k = 0; k < 64; ++k)
        a3 = fmaf(fe[k], p.W3[l * 384 + k * 6 + tid], a3);
      lgits[tid] = a3;
    }
    __syncthreads();
    if (tid == 0) {
      int idx = 0;
      float best = -INFINITY;
#pragma unroll
      for (int m2 = 0; m2 < 6; ++m2)
        if (d_LEGAL[tier][m2] && lgits[m2] > best) { best = lgits[m2]; idx = m2; }
      const float par = d_PARITY[idx];
      scal[0] = (idx == 1) ? 0.1f : ((idx == 5) ? -0.1f : 0.f);
      scal[1] = (idx == 4) ? 1.f : 0.f;
      scal[2] = (1.f + par * (p.aplK[l * 6 + idx] * z) * 0.5f) * 0.1f *
                p.Kglob[l] * (1.f / 60.f);
      scal[3] = p.aplOm[l * 6 + idx] * par;
    }
    __syncthreads();
    const float coef = scal[0], dmn = scal[1], ktot = scal[2], omadd = scal[3];

    // ---- state mods (mean & pre-mod coh per col, cross-wave) ----
    float psum = 0.f, pcc = 0.f, pss = 0.f;
#pragma unroll
    for (int r = 0; r < 4; ++r) { psum += th[r]; pcc += c4[r]; pss += s4[r]; }
    psum += __shfl_xor(psum, 16); psum += __shfl_xor(psum, 32);
    pcc += __shfl_xor(pcc, 16);  pcc += __shfl_xor(pcc, 32);
    pss += __shfl_xor(pss, 16);  pss += __shfl_xor(pss, 32);
    redM[w][c][0] = psum; redM[w][c][1] = pcc; redM[w][c][2] = pss;
    __syncthreads();
    {
      float tsum = 0.f, tc = 0.f, ts = 0.f;
#pragma unroll
      for (int ww = 0; ww < 4; ++ww) {
        tsum += redM[ww][c][0]; tc += redM[ww][c][1]; ts += redM[ww][c][2];
      }
      const float mean = tsum * (1.f / 60.f);
      const float mcp = (tc - 4.f) * (1.f / 60.f);
      const float msp = ts * (1.f / 60.f);
      const float ch_pre = sqrtf(mcp * mcp + msp * msp);
      if (coef != 0.f && !pad) {
#pragma unroll
        for (int r = 0; r < 4; ++r) th[r] += coef * __sinf(mean - th[r]);
      }
      if (dmn != 0.f && !pad) {
        const float f = 0.05f * (1.f - ch_pre);
        const float4 n4 = *(const float4*)(p.noise + (size_t)l * 491520 +
                                           (size_t)b * 60 + 16 * w + 4 * g);
        th[0] = fmaf(f, n4.x, th[0]); th[1] = fmaf(f, n4.y, th[1]);
        th[2] = fmaf(f, n4.z, th[2]); th[3] = fmaf(f, n4.w, th[3]);
      }
    }
    float om4[4];
    if (!pad) {
      const float4 o4 = *(const float4*)(p.omega + l * 60 + 16 * w + 4 * g);
      om4[0] = 0.1f * (o4.x + omadd); om4[1] = 0.1f * (o4.y + omadd);
      om4[2] = 0.1f * (o4.z + omadd); om4[3] = 0.1f * (o4.w + omadd);
    } else {
#pragma unroll
      for (int r = 0; r < 4; ++r) om4[r] = 0.f;
    }
#pragma unroll
    for (int r = 0; r < 4; ++r) { s4[r] = __sinf(th[r]); c4[r] = __cosf(th[r]); }

    // ---- A fragments ----
    const bf16x8v Af0 =
        *(const bf16x8v*)(p.Kb + l * 4096 + (16 * w + c) * 64 + 8 * g);
    const bf16x8v Af1 =
        *(const bf16x8v*)(p.Kb + l * 4096 + (16 * w + c) * 64 + 32 + 8 * g);
    const int wr = c * LSTR + 8 * w + 2 * g;

    // ---- 10 steps ----
    for (int step = 0; step < 10; ++step) {
      *(uint2*)&sinL[wr] = make_uint2(pkbf(s4[0], s4[1]), pkbf(s4[2], s4[3]));
      *(uint2*)&cosL[wr] = make_uint2(pkbf(c4[0], c4[1]), pkbf(c4[2], c4[3]));
      __syncthreads();
      const int rb = c * LSTR + 4 * g;
      const bf16x8v BS0 = __builtin_bit_cast(bf16x8v, *(const u32x4v*)&sinL[rb]);
      const bf16x8v BS1 = __builtin_bit_cast(bf16x8v, *(const u32x4v*)&sinL[rb + 16]);
      const bf16x8v BC0 = __builtin_bit_cast(bf16x8v, *(const u32x4v*)&cosL[rb]);
      const bf16x8v BC1 = __builtin_bit_cast(bf16x8v, *(const u32x4v*)&cosL[rb + 16]);
      f32x4v t0 = __builtin_amdgcn_mfma_f32_16x16x32_bf16(Af0, BS0, z4, 0, 0, 0);
      const f32x4v P = __builtin_amdgcn_mfma_f32_16x16x32_bf16(Af1, BS1, t0, 0, 0, 0);
      f32x4v t1 = __builtin_amdgcn_mfma_f32_16x16x32_bf16(Af0, BC0, z4, 0, 0, 0);
      const f32x4v Q = __builtin_amdgcn_mfma_f32_16x16x32_bf16(Af1, BC1, t1, 0, 0, 0);
#pragma unroll
      for (int r = 0; r < 4; ++r) {
        const float csum = c4[r] * P[r] - s4[r] * Q[r];
        const float d = fmaf(ktot, csum, om4[r]);
        th[r] += d;
        s4[r] = __sinf(th[r]);
        c4[r] = __cosf(th[r]);
      }
      __syncthreads();
    }

    // ---- epilogue: coherence per col ----
    float pc2 = 0.f, ps2 = 0.f;
#pragma unroll
    for (int r = 0; r < 4; ++r) { pc2 += c4[r]; ps2 += s4[r]; }
    pc2 += __shfl_xor(pc2, 16); pc2 += __shfl_xor(pc2, 32);
    ps2 += __shfl_xor(ps2, 16); ps2 += __shfl_xor(ps2, 32);
    redM[w][c][0] = pc2; redM[w][c][1] = ps2;
    __syncthreads();
    float tc2 = 0.f, ts2 = 0.f;
#pragma unroll
    for (int ww = 0; ww < 4; ++ww) { tc2 += redM[ww][c][0]; ts2 += redM[ww][c][1]; }
    const float mc2 = (tc2 - 4.f) * (1.f / 60.f);
    const float ms2 = ts2 * (1.f / 60.f);
    chcol = sqrtf(mc2 * mc2 + ms2 * ms2);

    if (l < 3) {
      // wrap theta (registers only)
#pragma unroll
      for (int r = 0; r < 4; ++r)
        th[r] = fmaf(-TWO_PI_F, rintf(th[r] * INV_2PI_F), th[r]);
      const float tot = wave_sum(chcol) * 0.25f;
      if (tid == 0) p.part[(l + 1) * 512 + bid] = tot;
      if (bid == 0) {
        if (c == 0 && !pad) {
          float* r0n = p.row0cos + 64 * ((l + 1) & 1);
#pragma unroll
          for (int r = 0; r < 4; ++r) r0n[16 * w + 4 * g + r] = c4[r];
        }
        if (tid == 0) p.coh0[(l + 1) & 1] = chcol;
      }
      grd.sync();
    }
  }

  // ---- output GEMM from final register state ----
  {
    const int wr = c * LSTR + 8 * w + 2 * g;
    *(uint2*)&sinL[wr] = make_uint2(pkbf(s4[0], s4[1]), pkbf(s4[2], s4[3]));
    *(uint2*)&cosL[wr] = make_uint2(pkbf(c4[0], c4[1]), pkbf(c4[2], c4[3]));
    __syncthreads();
    const int rb = c * LSTR + 4 * g;
    const bf16x8v BS0 = __builtin_bit_cast(bf16x8v, *(const u32x4v*)&sinL[rb]);
    const bf16x8v BS1 = __builtin_bit_cast(bf16x8v, *(const u32x4v*)&sinL[rb + 16]);
    const bf16x8v BC0 = __builtin_bit_cast(bf16x8v, *(const u32x4v*)&cosL[rb]);
    const bf16x8v BC1 = __builtin_bit_cast(bf16x8v, *(const u32x4v*)&cosL[rb + 16]);
#pragma unroll
    for (int i = 0; i < 4; ++i) {
      const int mp = 4 * w + i;
      const unsigned short* ap = p.Wob + (16 * mp + c) * 128 + 8 * g;
      const bf16x8v A0 = *(const bf16x8v*)(ap);
      const bf16x8v A1 = *(const bf16x8v*)(ap + 32);
      const bf16x8v A2 = *(const bf16x8v*)(ap + 64);
      const bf16x8v A3 = *(const bf16x8v*)(ap + 96);
      f32x4v d = __builtin_amdgcn_mfma_f32_16x16x32_bf16(A0, BC0, z4, 0, 0, 0);
      d = __builtin_amdgcn_mfma_f32_16x16x32_bf16(A1, BC1, d, 0, 0, 0);
      d = __builtin_amdgcn_mfma_f32_16x16x32_bf16(A2, BS0, d, 0, 0, 0);
      d = __builtin_amdgcn_mfma_f32_16x16x32_bf16(A3, BS1, d, 0, 0, 0);
      const float4 bo = *(const float4*)(p.b_out + 16 * mp + 4 * g);
      *(float4*)(&trans[c][16 * mp + 4 * g]) =
          make_float4((d[0] + bo.x) * chcol, (d[1] + bo.y) * chcol,
                      (d[2] + bo.z) * chcol, (d[3] + bo.w) * chcol);
    }
    __syncthreads();
#pragma unroll
    for (int i = 0; i < 4; ++i) {
      const int t = tid + 256 * i;
      const int row = t >> 6, cw = t & 63;
      const float4 v = *(const float4*)(&trans[row][4 * cw]);
      *(float4*)(p.out + (size_t)(bid * 16 + row) * 256 + 4 * cw) = v;
    }
  }
}

// ---------------------------------------------------------------------------
// Workspace (bytes): part f32[2048] @0, row0cos f32[128] @8192, coh0 f32[2]
// @8704, Aenc u16[32768] @9216, Kb u16[16384] @74752, Wob u16[32768] @107520.
// Total ~173 KB.
// ---------------------------------------------------------------------------
extern "C" void kernel_launch(void* const* d_in, const int* in_sizes, int n_in,
                              void* d_out, int out_size, void* d_ws, size_t ws_size,
                              hipStream_t stream) {
  char* wsb = (char*)d_ws;
  Params h;
  h.x     = (const float*)d_in[0];
  h.W_enc = (const float*)d_in[1];
  h.b_enc = (const float*)d_in[2];
  h.K     = (const float*)d_in[3];
  h.omega = (const float*)d_in[4];
  h.Kglob = (const float*)d_in[5];
  h.aplK  = (const float*)d_in[6];
  h.aplOm = (const float*)d_in[7];
  h.W1    = (const float*)d_in[8];
  h.b1    = (const float*)d_in[9];
  h.W2    = (const float*)d_in[10];
  h.b2    = (const float*)d_in[11];
  h.W3    = (const float*)d_in[12];
  h.b3    = (const float*)d_in[13];
  h.prior = (const float*)d_in[14];
  h.noise = (const float*)d_in[15];
  h.W_out = (const float*)d_in[16];
  h.b_out = (const float*)d_in[17];
  h.part    = (float*)(wsb + 0);
  h.row0cos = (float*)(wsb + 8192);
  h.coh0    = (float*)(wsb + 8704);
  h.Aenc    = (unsigned short*)(wsb + 9216);
  h.Kb      = (unsigned short*)(wsb + 74752);
  h.Wob     = (unsigned short*)(wsb + 107520);
  h.out     = (float*)d_out;

  void* args[] = {&h};
  hipLaunchCooperativeKernel((const void*)fused_net, dim3(512), dim3(256),
                             args, 0, stream);
}

// Round 9
// 57.818 us; speedup vs baseline: 5.6687x; 5.6687x over previous
//
#include <hip/hip_runtime.h>
#include <hip/hip_bf16.h>
#include <math.h>

typedef __attribute__((ext_vector_type(8))) short bf16x8v;
typedef __attribute__((ext_vector_type(4))) float f32x4v;
typedef __attribute__((ext_vector_type(4))) unsigned u32x4v;

namespace {

constexpr float PI_F      = 3.14159265358979323846f;
constexpr float TWO_PI_F  = 6.28318530717958647692f;
constexpr float INV_2PI_F = 0.15915494309189533577f;
constexpr float ZC_F      = 0.86602540378443864676f;

__device__ __constant__ float d_BOUNDS[8] = {0.1f, 0.2f, 0.4f, 0.6f, 0.75f,
                                             0.8660254037844386f, 0.92f, 0.97f};
__device__ __constant__ float d_PARITY[6] = {1.f, -1.f, 1.f, 1.f, -1.f, -1.f};
__device__ __constant__ int d_LEGAL[9][6] = {
    {0, 0, 0, 1, 1, 1},
    {1, 0, 1, 0, 1, 1},
    {1, 1, 1, 0, 1, 1},
    {0, 1, 0, 1, 1, 1},
    {1, 1, 1, 1, 1, 1},
    {0, 1, 0, 1, 1, 1},
    {0, 1, 0, 1, 0, 0},
    {0, 1, 1, 1, 0, 0},
    {0, 1, 1, 1, 0, 0}};

__device__ __forceinline__ float wave_sum(float v) {
#pragma unroll
  for (int o = 32; o > 0; o >>= 1) v += __shfl_xor(v, o, 64);
  return v;
}

__device__ __forceinline__ float gelu_exact(float x) {
  return 0.5f * x * (1.0f + erff(x * 0.70710678118654752440f));
}

__device__ __forceinline__ unsigned short f2b(float v) {
  return __builtin_bit_cast(unsigned short, __float2bfloat16(v));
}

__device__ __forceinline__ unsigned pkbf(float a, float b) {
  return ((unsigned)f2b(b) << 16) | (unsigned)f2b(a);
}

}  // namespace

// LDS pair-array stride (dwords): 32 pairs + 4 pad -> 2-way bank alias (free).
#define LSTR 36

// ---------------------------------------------------------------------------
// MFMA encoder: theta = pi*tanh(x @ W_enc + b_enc). 512 blocks x 256 thr
// (4 waves); wave w owns osc tile w (rows 16w+4g+r), block owns 16 batch cols.
// A = W_enc^T converted bf16 on the fly (L1-cached scattered reads); B = x
// (coalesced float4). Writes theta (D-layout float4) + per-block coh partial.
// Tail: blocks 0..63 convert K->Kb bf16 padded; 64..191 W_out->Wob bf16.
// ---------------------------------------------------------------------------
__global__ __launch_bounds__(256, 2) void enc_mfma(
    const float* __restrict__ x, const float* __restrict__ W_enc,
    const float* __restrict__ b_enc, const float* __restrict__ K,
    const float* __restrict__ W_out, float* __restrict__ theta,
    float* __restrict__ part, unsigned short* __restrict__ Kb,
    unsigned short* __restrict__ Wob) {
  __shared__ float redM[4][16][2];
  const int tid = threadIdx.x;
  const int w = tid >> 6;
  const int lane = tid & 63;
  const int c = lane & 15, g = lane >> 4;
  const int bid = blockIdx.x;
  const int b = bid * 16 + c;
  const bool pad = (w == 3) && (g == 3);
  const int orow = 16 * w + c;
  const bool arow = (orow < 60);
  const f32x4v z4 = {0.f, 0.f, 0.f, 0.f};

  f32x4v em = z4;
  const float* xr = x + (size_t)b * 512 + 8 * g;
  const float* wr0 = W_enc + orow;  // [k*60 + orow]
#pragma unroll 2
  for (int kt = 0; kt < 16; ++kt) {
    const float4 u0 = *(const float4*)(xr + 32 * kt);
    const float4 u1 = *(const float4*)(xr + 32 * kt + 4);
    u32x4v bx;
    bx[0] = pkbf(u0.x, u0.y); bx[1] = pkbf(u0.z, u0.w);
    bx[2] = pkbf(u1.x, u1.y); bx[3] = pkbf(u1.z, u1.w);
    u32x4v ax;
    if (arow) {
      const float* wp = wr0 + (32 * kt + 8 * g) * 60;
      ax[0] = pkbf(wp[0], wp[60]);
      ax[1] = pkbf(wp[120], wp[180]);
      ax[2] = pkbf(wp[240], wp[300]);
      ax[3] = pkbf(wp[360], wp[420]);
    } else {
      ax[0] = ax[1] = ax[2] = ax[3] = 0u;
    }
    em = __builtin_amdgcn_mfma_f32_16x16x32_bf16(
        __builtin_bit_cast(bf16x8v, ax), __builtin_bit_cast(bf16x8v, bx), em,
        0, 0, 0);
  }
  float th[4], s4[4], c4[4];
  if (!pad) {
    const float4 be = *(const float4*)(b_enc + 16 * w + 4 * g);
    const float bea[4] = {be.x, be.y, be.z, be.w};
#pragma unroll
    for (int r = 0; r < 4; ++r) th[r] = PI_F * tanhf(em[r] + bea[r]);
  } else {
#pragma unroll
    for (int r = 0; r < 4; ++r) th[r] = 0.f;
  }
  float pcc = 0.f, pss = 0.f;
#pragma unroll
  for (int r = 0; r < 4; ++r) {
    s4[r] = __sinf(th[r]);
    c4[r] = __cosf(th[r]);
    pcc += c4[r]; pss += s4[r];
  }
  pcc += __shfl_xor(pcc, 16); pcc += __shfl_xor(pcc, 32);
  pss += __shfl_xor(pss, 16); pss += __shfl_xor(pss, 32);
  redM[w][c][0] = pcc; redM[w][c][1] = pss;
  if (!pad)
    *(float4*)(theta + (size_t)b * 60 + 16 * w + 4 * g) =
        make_float4(th[0], th[1], th[2], th[3]);
  __syncthreads();
  float tc = 0.f, ts = 0.f;
#pragma unroll
  for (int ww = 0; ww < 4; ++ww) { tc += redM[ww][c][0]; ts += redM[ww][c][1]; }
  const float mc = (tc - 4.f) * (1.f / 60.f);
  const float ms = ts * (1.f / 60.f);
  const float ch = sqrtf(mc * mc + ms * ms);
  const float tot = wave_sum(ch) * 0.25f;
  if (tid == 0) part[bid] = tot;

  // prep tails
  if (bid < 64) {  // Kb: 16384 elems
    const int t = bid * 256 + tid;
    const int l = t >> 12, rem = t & 4095, i = rem >> 6, k = rem & 63;
    Kb[t] = f2b((i < 60 && k < 60) ? K[l * 3600 + i * 60 + k] : 0.f);
  } else if (bid < 192) {  // Wob: 32768 elems
    const int t = (bid - 64) * 256 + tid;
    const int d = t >> 7, kk = t & 127, prt = kk >> 6, o = kk & 63;
    Wob[t] = f2b((o < 60) ? W_out[(prt * 60 + o) * 256 + d] : 0.f);
  }
}

// ---------------------------------------------------------------------------
// Fused decide + Kuramoto (+output for l==3). 512 blocks x 256 thr (4 waves).
// Decide: k-split MLP across all 256 threads (4 chunks x 64 outputs, LDS
// reduce). Steps: parity double-buffered sin/cos LDS, ONE barrier per step.
// ---------------------------------------------------------------------------
__global__ __launch_bounds__(256, 2) void kura_mfma(
    float* __restrict__ theta, const float* __restrict__ noiseL,
    const unsigned short* __restrict__ Kb, const unsigned short* __restrict__ Wob,
    const float* __restrict__ omega, const float* __restrict__ Kglob,
    const float* __restrict__ aplK, const float* __restrict__ aplOm,
    const float* __restrict__ W1, const float* __restrict__ b1,
    const float* __restrict__ W2, const float* __restrict__ b2,
    const float* __restrict__ W3, const float* __restrict__ b3,
    const float* __restrict__ prior, const float* __restrict__ b_out,
    float* __restrict__ part, float* __restrict__ out, int l) {
  __shared__ float fe[64], hh[64], lgits[8], scal[4];
  __shared__ float redD[4][64];
  __shared__ float redM[4][16][4];
  __shared__ unsigned sinL[2][16 * LSTR], cosL[2][16 * LSTR];
  __shared__ __align__(16) float trans[16][260];
  const int tid = threadIdx.x;
  const int w = tid >> 6;
  const int lane = tid & 63;
  const int c = lane & 15, g = lane >> 4;
  const int bid = blockIdx.x;
  const int b = bid * 16 + c;
  const bool pad = (w == 3) && (g == 3);
  const f32x4v z4 = {0.f, 0.f, 0.f, 0.f};
  const int o = tid & 63, chx = tid >> 6;

  // ---- decide: feats by wave 0 ----
  float z = 0.f;
  int tier = 0;
  if (tid < 64) {
    const float4 p0 = *(const float4*)(part + l * 512 + 8 * lane);
    const float4 p1 = *(const float4*)(part + l * 512 + 8 * lane + 4);
    z = wave_sum(p0.x + p0.y + p0.z + p0.w + p1.x + p1.y + p1.z + p1.w) *
        (1.f / 8192.f);
#pragma unroll
    for (int i = 0; i < 8; ++i) tier += (z >= d_BOUNDS[i]) ? 1 : 0;
    const float dsneg = expf(-36.f * (z - ZC_F) * (z - ZC_F));
    const float th0 = (tid < 60) ? theta[tid] : 0.f;
    const float c00 = __cosf(th0);
    const float pc0 = wave_sum((tid < 60) ? c00 : 0.f) * (1.f / 60.f);
    const float ps0 = wave_sum((tid < 60) ? __sinf(th0) : 0.f) * (1.f / 60.f);
    const float ch0 = sqrtf(pc0 * pc0 + ps0 * ps0);
    fe[tid] = (tid < 60) ? c00
            : (tid == 60) ? z
            : (tid == 61) ? ch0
            : (tid == 62) ? dsneg
                          : (float)(tier + 1) * (1.f / 9.f);
  }
  __syncthreads();
  // ---- W1 (k-split 4x16) ----
  {
    float a = 0.f;
    const float* Wp = W1 + l * 4096 + (16 * chx) * 64 + o;
#pragma unroll
    for (int kk = 0; kk < 16; ++kk) a = fmaf(fe[16 * chx + kk], Wp[kk * 64], a);
    redD[chx][o] = a;
  }
  __syncthreads();
  if (tid < 64)
    hh[tid] = gelu_exact(redD[0][tid] + redD[1][tid] + redD[2][tid] +
                         redD[3][tid] + b1[l * 64 + tid]);
  __syncthreads();
  // ---- W2 ----
  {
    float a = 0.f;
    const float* Wp = W2 + l * 4096 + (16 * chx) * 64 + o;
#pragma unroll
    for (int kk = 0; kk < 16; ++kk) a = fmaf(hh[16 * chx + kk], Wp[kk * 64], a);
    redD[chx][o] = a;
  }
  __syncthreads();
  if (tid < 64)
    fe[tid] = gelu_exact(redD[0][tid] + redD[1][tid] + redD[2][tid] +
                         redD[3][tid] + b2[l * 64 + tid]);
  __syncthreads();
  // ---- W3 (6 outputs, k-split) ----
  if (tid < 24) {
    const int o3 = tid >> 2, ch3 = tid & 3;
    float a = 0.f;
#pragma unroll
    for (int kk = 0; kk < 16; ++kk)
      a = fmaf(fe[16 * ch3 + kk], W3[l * 384 + (16 * ch3 + kk) * 6 + o3], a);
    redD[ch3][o3] = a;
  }
  __syncthreads();
  if (tid < 6)
    lgits[tid] = redD[0][tid] + redD[1][tid] + redD[2][tid] + redD[3][tid] +
                 b3[l * 6 + tid] + prior[l * 6 + tid];
  __syncthreads();
  if (tid == 0) {
    int idx = 0;
    float best = -INFINITY;
#pragma unroll
    for (int m2 = 0; m2 < 6; ++m2)
      if (d_LEGAL[tier][m2] && lgits[m2] > best) { best = lgits[m2]; idx = m2; }
    const float par = d_PARITY[idx];
    scal[0] = (idx == 1) ? 0.1f : ((idx == 5) ? -0.1f : 0.f);
    scal[1] = (idx == 4) ? 1.f : 0.f;
    scal[2] = (1.f + par * (aplK[l * 6 + idx] * z) * 0.5f) * 0.1f * Kglob[l] *
              (1.f / 60.f);
    scal[3] = aplOm[l * 6 + idx] * par;
  }
  __syncthreads();
  const float coef = scal[0], dmn = scal[1], ktot = scal[2], omadd = scal[3];

  // ---- state load ----
  float th[4], s4[4], c4[4], om4[4];
  if (!pad) {
    const float4 t4 = *(const float4*)(theta + (size_t)b * 60 + 16 * w + 4 * g);
    const float4 o4 = *(const float4*)(omega + l * 60 + 16 * w + 4 * g);
    th[0] = t4.x; th[1] = t4.y; th[2] = t4.z; th[3] = t4.w;
    om4[0] = 0.1f * (o4.x + omadd); om4[1] = 0.1f * (o4.y + omadd);
    om4[2] = 0.1f * (o4.z + omadd); om4[3] = 0.1f * (o4.w + omadd);
  } else {
#pragma unroll
    for (int r = 0; r < 4; ++r) { th[r] = 0.f; om4[r] = 0.f; }
  }

  // ---- entry mean + pre-mod coherence (cross-wave) ----
  float psum = 0.f, pcc = 0.f, pss = 0.f;
#pragma unroll
  for (int r = 0; r < 4; ++r) {
    psum += th[r];
    pcc += __cosf(th[r]);
    pss += __sinf(th[r]);
  }
  psum += __shfl_xor(psum, 16); psum += __shfl_xor(psum, 32);
  pcc += __shfl_xor(pcc, 16);  pcc += __shfl_xor(pcc, 32);
  pss += __shfl_xor(pss, 16);  pss += __shfl_xor(pss, 32);
  redM[w][c][0] = psum; redM[w][c][1] = pcc; redM[w][c][2] = pss;
  __syncthreads();
  {
    float tsum = 0.f, tc = 0.f, ts = 0.f;
#pragma unroll
    for (int ww = 0; ww < 4; ++ww) {
      tsum += redM[ww][c][0]; tc += redM[ww][c][1]; ts += redM[ww][c][2];
    }
    const float mean = tsum * (1.f / 60.f);
    const float mcp = (tc - 4.f) * (1.f / 60.f);
    const float msp = ts * (1.f / 60.f);
    const float ch_pre = sqrtf(mcp * mcp + msp * msp);
    if (coef != 0.f && !pad) {
#pragma unroll
      for (int r = 0; r < 4; ++r) th[r] += coef * __sinf(mean - th[r]);
    }
    if (dmn != 0.f && !pad) {
      const float f = 0.05f * (1.f - ch_pre);
      const float4 n4 =
          *(const float4*)(noiseL + (size_t)b * 60 + 16 * w + 4 * g);
      th[0] = fmaf(f, n4.x, th[0]); th[1] = fmaf(f, n4.y, th[1]);
      th[2] = fmaf(f, n4.z, th[2]); th[3] = fmaf(f, n4.w, th[3]);
    }
  }
#pragma unroll
  for (int r = 0; r < 4; ++r) { s4[r] = __sinf(th[r]); c4[r] = __cosf(th[r]); }

  // ---- A fragments ----
  const bf16x8v Af0 =
      *(const bf16x8v*)(Kb + l * 4096 + (16 * w + c) * 64 + 8 * g);
  const bf16x8v Af1 =
      *(const bf16x8v*)(Kb + l * 4096 + (16 * w + c) * 64 + 32 + 8 * g);
  const int wr = c * LSTR + 8 * w + 2 * g;
  const int rb = c * LSTR + 4 * g;

  // ---- 10 steps, ONE barrier each (parity double buffer) ----
  for (int step = 0; step < 10; ++step) {
    const int pb = step & 1;
    *(uint2*)&sinL[pb][wr] = make_uint2(pkbf(s4[0], s4[1]), pkbf(s4[2], s4[3]));
    *(uint2*)&cosL[pb][wr] = make_uint2(pkbf(c4[0], c4[1]), pkbf(c4[2], c4[3]));
    __syncthreads();
    const bf16x8v BS0 = __builtin_bit_cast(bf16x8v, *(const u32x4v*)&sinL[pb][rb]);
    const bf16x8v BS1 = __builtin_bit_cast(bf16x8v, *(const u32x4v*)&sinL[pb][rb + 16]);
    const bf16x8v BC0 = __builtin_bit_cast(bf16x8v, *(const u32x4v*)&cosL[pb][rb]);
    const bf16x8v BC1 = __builtin_bit_cast(bf16x8v, *(const u32x4v*)&cosL[pb][rb + 16]);
    f32x4v t0 = __builtin_amdgcn_mfma_f32_16x16x32_bf16(Af0, BS0, z4, 0, 0, 0);
    const f32x4v P = __builtin_amdgcn_mfma_f32_16x16x32_bf16(Af1, BS1, t0, 0, 0, 0);
    f32x4v t1 = __builtin_amdgcn_mfma_f32_16x16x32_bf16(Af0, BC0, z4, 0, 0, 0);
    const f32x4v Q = __builtin_amdgcn_mfma_f32_16x16x32_bf16(Af1, BC1, t1, 0, 0, 0);
#pragma unroll
    for (int r = 0; r < 4; ++r) {
      const float csum = c4[r] * P[r] - s4[r] * Q[r];
      const float d = fmaf(ktot, csum, om4[r]);
      th[r] += d;
      s4[r] = __sinf(th[r]);
      c4[r] = __cosf(th[r]);
    }
  }

  // ---- epilogue: coherence per col ----
  float pc2 = 0.f, ps2 = 0.f;
#pragma unroll
  for (int r = 0; r < 4; ++r) { pc2 += c4[r]; ps2 += s4[r]; }
  pc2 += __shfl_xor(pc2, 16); pc2 += __shfl_xor(pc2, 32);
  ps2 += __shfl_xor(ps2, 16); ps2 += __shfl_xor(ps2, 32);
  redM[w][c][0] = pc2; redM[w][c][1] = ps2;
  __syncthreads();
  float tc2 = 0.f, ts2 = 0.f;
#pragma unroll
  for (int ww = 0; ww < 4; ++ww) { tc2 += redM[ww][c][0]; ts2 += redM[ww][c][1]; }
  const float mc2 = (tc2 - 4.f) * (1.f / 60.f);
  const float ms2 = ts2 * (1.f / 60.f);
  const float ch = sqrtf(mc2 * mc2 + ms2 * ms2);

  if (l < 3) {
    if (!pad) {
      float wv[4];
#pragma unroll
      for (int r = 0; r < 4; ++r)
        wv[r] = fmaf(-TWO_PI_F, rintf(th[r] * INV_2PI_F), th[r]);
      *(float4*)(theta + (size_t)b * 60 + 16 * w + 4 * g) =
          make_float4(wv[0], wv[1], wv[2], wv[3]);
    }
    const float tot = wave_sum(ch) * 0.25f;
    if (tid == 0) part[(l + 1) * 512 + bid] = tot;
    return;
  }

  // ---- l==3: output GEMM from final state (parity buffer 0, fresh) ----
  *(uint2*)&sinL[0][wr] = make_uint2(pkbf(s4[0], s4[1]), pkbf(s4[2], s4[3]));
  *(uint2*)&cosL[0][wr] = make_uint2(pkbf(c4[0], c4[1]), pkbf(c4[2], c4[3]));
  __syncthreads();
  const bf16x8v BS0 = __builtin_bit_cast(bf16x8v, *(const u32x4v*)&sinL[0][rb]);
  const bf16x8v BS1 = __builtin_bit_cast(bf16x8v, *(const u32x4v*)&sinL[0][rb + 16]);
  const bf16x8v BC0 = __builtin_bit_cast(bf16x8v, *(const u32x4v*)&cosL[0][rb]);
  const bf16x8v BC1 = __builtin_bit_cast(bf16x8v, *(const u32x4v*)&cosL[0][rb + 16]);
#pragma unroll
  for (int i = 0; i < 4; ++i) {
    const int mp = 4 * w + i;
    const unsigned short* ap = Wob + (16 * mp + c) * 128 + 8 * g;
    const bf16x8v A0 = *(const bf16x8v*)(ap);
    const bf16x8v A1 = *(const bf16x8v*)(ap + 32);
    const bf16x8v A2 = *(const bf16x8v*)(ap + 64);
    const bf16x8v A3 = *(const bf16x8v*)(ap + 96);
    f32x4v d = __builtin_amdgcn_mfma_f32_16x16x32_bf16(A0, BC0, z4, 0, 0, 0);
    d = __builtin_amdgcn_mfma_f32_16x16x32_bf16(A1, BC1, d, 0, 0, 0);
    d = __builtin_amdgcn_mfma_f32_16x16x32_bf16(A2, BS0, d, 0, 0, 0);
    d = __builtin_amdgcn_mfma_f32_16x16x32_bf16(A3, BS1, d, 0, 0, 0);
    const float4 bo = *(const float4*)(b_out + 16 * mp + 4 * g);
    *(float4*)(&trans[c][16 * mp + 4 * g]) =
        make_float4((d[0] + bo.x) * ch, (d[1] + bo.y) * ch,
                    (d[2] + bo.z) * ch, (d[3] + bo.w) * ch);
  }
  __syncthreads();
#pragma unroll
  for (int i = 0; i < 4; ++i) {
    const int t = tid + 256 * i;
    const int row = t >> 6, cw = t & 63;
    const float4 v = *(const float4*)(&trans[row][4 * cw]);
    *(float4*)(out + (size_t)(bid * 16 + row) * 256 + 4 * cw) = v;
  }
}

// ---------------------------------------------------------------------------
// Workspace (float offsets): theta [491520] @0, part [2048] @491520,
// Kb u16[16384] @493568, Wob u16[32768] @501760. Total ~2.03 MB.
// ---------------------------------------------------------------------------
extern "C" void kernel_launch(void* const* d_in, const int* in_sizes, int n_in,
                              void* d_out, int out_size, void* d_ws, size_t ws_size,
                              hipStream_t stream) {
  const float* x     = (const float*)d_in[0];
  const float* W_enc = (const float*)d_in[1];
  const float* b_enc = (const float*)d_in[2];
  const float* K     = (const float*)d_in[3];
  const float* omega = (const float*)d_in[4];
  const float* Kglob = (const float*)d_in[5];
  const float* aplK  = (const float*)d_in[6];
  const float* aplOm = (const float*)d_in[7];
  const float* W1    = (const float*)d_in[8];
  const float* b1    = (const float*)d_in[9];
  const float* W2    = (const float*)d_in[10];
  const float* b2    = (const float*)d_in[11];
  const float* W3    = (const float*)d_in[12];
  const float* b3    = (const float*)d_in[13];
  const float* prior = (const float*)d_in[14];
  const float* noise = (const float*)d_in[15];
  const float* W_out = (const float*)d_in[16];
  const float* b_out = (const float*)d_in[17];

  float* ws    = (float*)d_ws;
  float* theta = ws;
  float* part  = ws + 491520;
  unsigned short* Kb  = (unsigned short*)(ws + 493568);
  unsigned short* Wob = (unsigned short*)(ws + 501760);

  enc_mfma<<<512, 256, 0, stream>>>(x, W_enc, b_enc, K, W_out,
                                    theta, part, Kb, Wob);
  for (int l = 0; l < 4; ++l) {
    kura_mfma<<<512, 256, 0, stream>>>(theta, noise + (size_t)l * 491520,
                                       Kb, Wob, omega, Kglob, aplK, aplOm,
                                       W1, b1, W2, b2, W3, b3, prior, b_out,
                                       part, (float*)d_out, l);
  }
}